// Round 3
// baseline (545.995 us; speedup 1.0000x reference)
//
#include <hip/hip_runtime.h>
#include <hip/hip_bf16.h>

typedef unsigned short u16;
typedef __attribute__((ext_vector_type(8))) short short8;
typedef __attribute__((ext_vector_type(4))) float f32x4;

#define N_AGENTS 131072
#define HID 128
#define FUT 12
#define OBS 8

constexpr int M_TILE = 16;   // agents per tile
constexpr int AG     = 4;    // tiles processed per block

__device__ __forceinline__ u16 f2bf(float f) {
    union { float f; unsigned int i; } v; v.f = f;
    unsigned int u = v.i;
    return (u16)((u + 0x7fffu + ((u >> 16) & 1u)) >> 16);
}
// raw transcendental units — no libcall, no edge-case code
__device__ __forceinline__ float vexp2(float x) {
    float r; asm("v_exp_f32 %0, %1" : "=v"(r) : "v"(x)); return r;
}
__device__ __forceinline__ float vrcp(float x) {
    float r; asm("v_rcp_f32 %0, %1" : "=v"(r) : "v"(x)); return r;
}
__device__ __forceinline__ float sigm(float x) {
    return vrcp(1.0f + vexp2(-1.4426950408889634f * x));
}
__device__ __forceinline__ float tanh_(float x) {
    return 2.0f * vrcp(1.0f + vexp2(-2.8853900817779268f * x)) - 1.0f;
}

__launch_bounds__(256, 2)
__global__ void lstm_dec_kernel(const float* __restrict__ obs,
                                const float* __restrict__ h0g,
                                const float* __restrict__ Wih,
                                const float* __restrict__ Whh,
                                const float* __restrict__ bih,
                                const float* __restrict__ bhh,
                                const float* __restrict__ Wout,
                                const float* __restrict__ bout,
                                float* __restrict__ dout)
{
    // h tile double-buffered (bf16): rows padded to 17*short8 = 136 u16 = 272B
    __shared__ short8 hb[2][M_TILE][17];
    __shared__ float  xt[M_TILE][2];
    __shared__ float  ot[FUT][M_TILE][2];   // staged outputs, flushed per tile

    const int tid  = threadIdx.x;
    const int lane = tid & 63;
    const int wv   = tid >> 6;      // wave 0..3, owns hidden [32*wv, 32*wv+32)
    const int r    = lane & 15;     // row (A) / col (B/D) index within 16-tile
    const int kb   = lane >> 4;     // k-block of 8 elems; also D row-block

    const float bout0 = bout[0];
    const float bout1 = bout[1];

    // per-lane gate-column constants: nt 0..7 -> gate type (nt>>1), sub (nt&1)
    int   cols[8];
    float wih0[8], wih1[8], beff[8];
#pragma unroll
    for (int nt = 0; nt < 8; ++nt) {
        int c = (nt >> 1) * 128 + wv * 32 + (nt & 1) * 16 + r;
        cols[nt] = c;
        wih0[nt] = Wih[c * 2 + 0];
        wih1[nt] = Wih[c * 2 + 1];
        beff[nt] = bih[c] + bhh[c] + wih0[nt] * bout0 + wih1[nt] * bout1;
    }

    // build W_eff = W_hh + W_ih @ W_out b-fragments (bf16) in registers
    short8 bfrag[8][4];
    short8 outb[4];
#pragma unroll
    for (int kf = 0; kf < 4; ++kf) {
        const int k0 = kf * 32 + kb * 8;
        float wo0[8], wo1[8];
        short8 ob;
#pragma unroll
        for (int j = 0; j < 8; ++j) {
            wo0[j] = Wout[0 * HID + k0 + j];
            wo1[j] = Wout[1 * HID + k0 + j];
            float sel = (r == 0) ? wo0[j] : ((r == 1) ? wo1[j] : 0.0f);
            ob[j] = (short)f2bf(sel);
        }
        outb[kf] = ob;
#pragma unroll
        for (int nt = 0; nt < 8; ++nt) {
            short8 t;
#pragma unroll
            for (int j = 0; j < 8; ++j) {
                float f = Whh[cols[nt] * HID + k0 + j]
                        + wih0[nt] * wo0[j] + wih1[nt] * wo1[j];
                t[j] = (short)f2bf(f);
            }
            bfrag[nt][kf] = t;
        }
    }

    for (int t = 0; t < AG; ++t) {
        const int A0 = (blockIdx.x * AG + t) * M_TILE;

        // prefetch obs x0 for this tile (used in s==0 correction)
        float ox0[4], ox1[4];
#pragma unroll
        for (int q = 0; q < 4; ++q) {
            const float* op = obs + ((size_t)(OBS - 1) * N_AGENTS + A0 + kb * 4 + q) * 2;
            ox0[q] = op[0];
            ox1[q] = op[1];
        }

        f32x4 cfr[2];
#pragma unroll
        for (int sub = 0; sub < 2; ++sub) cfr[sub] = f32x4{0.f, 0.f, 0.f, 0.f};

        short8 afrag[4];
        for (int s = 0; s <= FUT; ++s) {
            // ---- A fragments: h(s-1), row = r (agent), k = kf*32 + kb*8 ----
            if (s == 0) {
#pragma unroll
                for (int kf = 0; kf < 4; ++kf) {
                    const float* hp = h0g + (size_t)(A0 + r) * HID + kf * 32 + kb * 8;
                    f32x4 lo = *(const f32x4*)(hp);
                    f32x4 hi = *(const f32x4*)(hp + 4);
                    short8 a;
#pragma unroll
                    for (int j = 0; j < 4; ++j) { a[j] = (short)f2bf(lo[j]); a[4 + j] = (short)f2bf(hi[j]); }
                    afrag[kf] = a;
                }
            } else {
                const int rb = (s - 1) & 1;
#pragma unroll
                for (int kf = 0; kf < 4; ++kf)
                    afrag[kf] = hb[rb][r][kf * 4 + kb];
            }

            // ---- gate GEMM (bias pre-folded into C-in) ----
            f32x4 acc[8];
            if (s < FUT) {
#pragma unroll
                for (int nt = 0; nt < 8; ++nt)
                    acc[nt] = f32x4{beff[nt], beff[nt], beff[nt], beff[nt]};
#pragma unroll
                for (int kf = 0; kf < 4; ++kf) {
#pragma unroll
                    for (int nt = 0; nt < 8; ++nt)
                        acc[nt] = __builtin_amdgcn_mfma_f32_16x16x32_bf16(
                            afrag[kf], bfrag[nt][kf], acc[nt], 0, 0, 0);
                }
            }

            // ---- out tile (wave 0): h(s-1) @ W_out^T ----
            if (wv == 0) {
                f32x4 oacc = {0.f, 0.f, 0.f, 0.f};
#pragma unroll
                for (int kf = 0; kf < 4; ++kf)
                    oacc = __builtin_amdgcn_mfma_f32_16x16x32_bf16(
                        afrag[kf], outb[kf], oacc, 0, 0, 0);
                if (r < 2) {
                    const float bo = (r == 0) ? bout0 : bout1;
                    if (s == 0) {
#pragma unroll
                        for (int q = 0; q < 4; ++q)
                            xt[kb * 4 + q][r] = oacc[q] + bo;
                    } else {
#pragma unroll
                        for (int q = 0; q < 4; ++q)
                            ot[s - 1][kb * 4 + q][r] = oacc[q] + bo;
                    }
                }
            }

            // ---- step-0 exact correction: gates += (x0 - x~0) @ W_ih^T ----
            if (s == 0) {
                __syncthreads();  // x~0 visible
#pragma unroll
                for (int q = 0; q < 4; ++q) {
                    int a  = kb * 4 + q;
                    float dx0 = ox0[q] - xt[a][0];
                    float dx1 = ox1[q] - xt[a][1];
#pragma unroll
                    for (int nt = 0; nt < 8; ++nt)
                        acc[nt][q] += dx0 * wih0[nt] + dx1 * wih1[nt];
                }
            }

            // ---- activations + c/h update, write h(s) to LDS (bf16) ----
            if (s < FUT) {
                const int wb = s & 1;
                u16* hbase = (u16*)&hb[wb][0][0];
#pragma unroll
                for (int sub = 0; sub < 2; ++sub) {
#pragma unroll
                    for (int q = 0; q < 4; ++q) {
                        float iv = sigm (acc[0 + sub][q]);
                        float fv = sigm (acc[2 + sub][q]);
                        float gv = tanh_(acc[4 + sub][q]);
                        float ov = sigm (acc[6 + sub][q]);
                        float cn = fv * cfr[sub][q] + iv * gv;
                        cfr[sub][q] = cn;
                        float hv = ov * tanh_(cn);
                        int row = kb * 4 + q;                 // agent
                        int col = wv * 32 + sub * 16 + r;     // hidden idx
                        hbase[row * 136 + col] = f2bf(hv);
                    }
                }
            }
            __syncthreads();
        }

        // ---- coalesced output flush (safe: next ot write is 2 barriers away) ----
        if (lane < 32) {
            const float* otf = &ot[0][0][0];
#pragma unroll
            for (int s2 = wv; s2 < FUT; s2 += 4)
                dout[((size_t)s2 * N_AGENTS + A0) * 2 + lane] = otf[s2 * 32 + lane];
        }
    }
}

extern "C" void kernel_launch(void* const* d_in, const int* in_sizes, int n_in,
                              void* d_out, int out_size, void* d_ws, size_t ws_size,
                              hipStream_t stream) {
    const float* obs  = (const float*)d_in[0];
    // d_in[1] (fut_traj_rel) is unused by the reference
    const float* h0   = (const float*)d_in[2];
    const float* Wih  = (const float*)d_in[3];
    const float* Whh  = (const float*)d_in[4];
    const float* bih  = (const float*)d_in[5];
    const float* bhh  = (const float*)d_in[6];
    const float* Wout = (const float*)d_in[7];
    const float* bo   = (const float*)d_in[8];
    float* out = (float*)d_out;

    dim3 grid(N_AGENTS / (M_TILE * AG));   // 2048 blocks
    lstm_dec_kernel<<<grid, 256, 0, stream>>>(obs, h0, Wih, Whh, bih, bhh, Wout, bo, out);
}

// Round 4
// 397.087 us; speedup vs baseline: 1.3750x; 1.3750x over previous
//
#include <hip/hip_runtime.h>

typedef unsigned short u16;
typedef __attribute__((ext_vector_type(8))) short short8;
typedef __attribute__((ext_vector_type(4))) float f32x4;

#define N_AGENTS 131072
#define HID 128
#define FUT 12
#define OBS 8

constexpr int M_TILE = 16;   // agents per tile
constexpr int AG     = 8;    // tiles per block

__device__ __forceinline__ u16 f2bf(float f) {
    union { float f; unsigned int i; } v; v.f = f;
    unsigned int u = v.i;
    return (u16)((u + 0x7fffu + ((u >> 16) & 1u)) >> 16);
}
__device__ __forceinline__ float vexp2(float x) {
    float r; asm("v_exp_f32 %0, %1" : "=v"(r) : "v"(x)); return r;
}
__device__ __forceinline__ float vrcp(float x) {
    float r; asm("v_rcp_f32 %0, %1" : "=v"(r) : "v"(x)); return r;
}
__device__ __forceinline__ float sigm(float x) {
    return vrcp(1.0f + vexp2(-1.4426950408889634f * x));
}
__device__ __forceinline__ float tanh_(float x) {
    return 2.0f * vrcp(1.0f + vexp2(-2.8853900817779268f * x)) - 1.0f;
}

__launch_bounds__(512, 2)
__global__ void lstm_dec_kernel(const float* __restrict__ obs,
                                const float* __restrict__ h0g,
                                const float* __restrict__ Wih,
                                const float* __restrict__ Whh,
                                const float* __restrict__ bih,
                                const float* __restrict__ bhh,
                                const float* __restrict__ Wout,
                                const float* __restrict__ bout,
                                float* __restrict__ dout)
{
    // h tile double-buffered (bf16): rows padded to 17*short8 = 136 u16
    __shared__ short8 hb[2][M_TILE][17];
    __shared__ float  xt[M_TILE][2];
    __shared__ float  ot[FUT][M_TILE][2];   // staged outputs, flushed per tile

    const int tid  = threadIdx.x;
    const int lane = tid & 63;
    const int wv   = tid >> 6;      // wave 0..7, owns hidden [16*wv, 16*wv+16)
    const int r    = lane & 15;     // row (A) / col (B/D) index within 16-tile
    const int kb   = lane >> 4;     // k-block of 8 elems; also D row-block

    const float bout0 = bout[0];
    const float bout1 = bout[1];

    // per-lane gate-column constants: nt = gate (i,f,g,o)
    int   cols[4];
    float wih0[4], wih1[4], beff[4];
#pragma unroll
    for (int nt = 0; nt < 4; ++nt) {
        int c = nt * HID + wv * 16 + r;
        cols[nt] = c;
        wih0[nt] = Wih[c * 2 + 0];
        wih1[nt] = Wih[c * 2 + 1];
        beff[nt] = bih[c] + bhh[c] + wih0[nt] * bout0 + wih1[nt] * bout1;
    }

    // W_eff = W_hh + W_ih @ W_out b-fragments (bf16), 64 VGPRs per lane
    short8 bfrag[4][4];
    short8 outb[4];
#pragma unroll
    for (int kf = 0; kf < 4; ++kf) {
        const int k0 = kf * 32 + kb * 8;
        float wo0[8], wo1[8];
        short8 ob;
#pragma unroll
        for (int j = 0; j < 8; ++j) {
            wo0[j] = Wout[0 * HID + k0 + j];
            wo1[j] = Wout[1 * HID + k0 + j];
            float sel = (r == 0) ? wo0[j] : ((r == 1) ? wo1[j] : 0.0f);
            ob[j] = (short)f2bf(sel);
        }
        outb[kf] = ob;
#pragma unroll
        for (int nt = 0; nt < 4; ++nt) {
            short8 tt;
#pragma unroll
            for (int j = 0; j < 8; ++j) {
                float f = Whh[(size_t)cols[nt] * HID + k0 + j]
                        + wih0[nt] * wo0[j] + wih1[nt] * wo1[j];
                tt[j] = (short)f2bf(f);
            }
            bfrag[nt][kf] = tt;
        }
    }

#pragma unroll 1
    for (int t = 0; t < AG; ++t) {
        const int A0 = (blockIdx.x * AG + t) * M_TILE;

        // cooperative coalesced h0 preload -> hb[1] (bf16)
        {
            int row = tid >> 5;          // 16 rows, 32 threads/row
            int c4  = (tid & 31) * 4;
            const float* hp = h0g + (size_t)(A0 + row) * HID + c4;
            f32x4 v = *(const f32x4*)hp;
            u16* dst = (u16*)&hb[1][0][0] + row * 136 + c4;
            dst[0] = f2bf(v[0]); dst[1] = f2bf(v[1]);
            dst[2] = f2bf(v[2]); dst[3] = f2bf(v[3]);
        }
        // prefetch obs x0 for this tile
        float ox0[4], ox1[4];
#pragma unroll
        for (int q = 0; q < 4; ++q) {
            const float* op = obs + ((size_t)(OBS - 1) * N_AGENTS + A0 + kb * 4 + q) * 2;
            ox0[q] = op[0];
            ox1[q] = op[1];
        }
        f32x4 cfr = {0.f, 0.f, 0.f, 0.f};
        __syncthreads();

#pragma unroll 1
        for (int s = 0; s <= FUT; ++s) {
            // ---- A fragments: h(s-1) from hb[(s+1)&1] ----
            short8 afrag[4];
            const int rb = (s + 1) & 1;
#pragma unroll
            for (int kf = 0; kf < 4; ++kf)
                afrag[kf] = hb[rb][r][kf * 4 + kb];

            // ---- gate GEMM (bias pre-folded into C-in) ----
            f32x4 acc[4];
            if (s < FUT) {
#pragma unroll
                for (int nt = 0; nt < 4; ++nt)
                    acc[nt] = f32x4{beff[nt], beff[nt], beff[nt], beff[nt]};
#pragma unroll
                for (int kf = 0; kf < 4; ++kf) {
#pragma unroll
                    for (int nt = 0; nt < 4; ++nt)
                        acc[nt] = __builtin_amdgcn_mfma_f32_16x16x32_bf16(
                            afrag[kf], bfrag[nt][kf], acc[nt], 0, 0, 0);
                }
            }

            // ---- out tile (wave 0): h(s-1) @ W_out^T ----
            if (wv == 0) {
                f32x4 oacc = {0.f, 0.f, 0.f, 0.f};
#pragma unroll
                for (int kf = 0; kf < 4; ++kf)
                    oacc = __builtin_amdgcn_mfma_f32_16x16x32_bf16(
                        afrag[kf], outb[kf], oacc, 0, 0, 0);
                if (r < 2) {
                    const float bo = (r == 0) ? bout0 : bout1;
                    if (s == 0) {
#pragma unroll
                        for (int q = 0; q < 4; ++q)
                            xt[kb * 4 + q][r] = oacc[q] + bo;
                    } else {
#pragma unroll
                        for (int q = 0; q < 4; ++q)
                            ot[s - 1][kb * 4 + q][r] = oacc[q] + bo;
                    }
                }
            }

            // ---- step-0 exact correction: gates += (x0 - x~0) @ W_ih^T ----
            if (s == 0) {
                __syncthreads();  // x~0 visible
#pragma unroll
                for (int q = 0; q < 4; ++q) {
                    float dx0 = ox0[q] - xt[kb * 4 + q][0];
                    float dx1 = ox1[q] - xt[kb * 4 + q][1];
#pragma unroll
                    for (int nt = 0; nt < 4; ++nt)
                        acc[nt][q] += dx0 * wih0[nt] + dx1 * wih1[nt];
                }
            }

            // ---- activations + c/h update, write h(s) to LDS (bf16) ----
            if (s < FUT) {
                u16* hbase = (u16*)&hb[s & 1][0][0];
#pragma unroll
                for (int q = 0; q < 4; ++q) {
                    float iv = sigm (acc[0][q]);
                    float fv = sigm (acc[1][q]);
                    float gv = tanh_(acc[2][q]);
                    float ov = sigm (acc[3][q]);
                    float cn = fv * cfr[q] + iv * gv;
                    cfr[q] = cn;
                    float hv = ov * tanh_(cn);
                    hbase[(kb * 4 + q) * 136 + wv * 16 + r] = f2bf(hv);
                }
            }
            __syncthreads();
        }

        // ---- coalesced output flush (384 threads, 128B per 32-lane group) ----
        if (tid < 32 * FUT) {
            const float* otf = &ot[0][0][0];
            dout[((size_t)(tid >> 5) * N_AGENTS + A0) * 2 + (tid & 31)] = otf[tid];
        }
        // safe: next ot write (tile t+1, s==1) is >=2 barriers after these reads
    }
}

extern "C" void kernel_launch(void* const* d_in, const int* in_sizes, int n_in,
                              void* d_out, int out_size, void* d_ws, size_t ws_size,
                              hipStream_t stream) {
    const float* obs  = (const float*)d_in[0];
    // d_in[1] (fut_traj_rel) is unused by the reference
    const float* h0   = (const float*)d_in[2];
    const float* Wih  = (const float*)d_in[3];
    const float* Whh  = (const float*)d_in[4];
    const float* bih  = (const float*)d_in[5];
    const float* bhh  = (const float*)d_in[6];
    const float* Wout = (const float*)d_in[7];
    const float* bo   = (const float*)d_in[8];
    float* out = (float*)d_out;

    dim3 grid(N_AGENTS / (M_TILE * AG));   // 1024 blocks of 512 threads
    lstm_dec_kernel<<<grid, 512, 0, stream>>>(obs, h0, Wih, Whh, bih, bhh, Wout, bo, out);
}

// Round 5
// 372.685 us; speedup vs baseline: 1.4650x; 1.0655x over previous
//
#include <hip/hip_runtime.h>

typedef unsigned short u16;
typedef __attribute__((ext_vector_type(8))) short short8;
typedef __attribute__((ext_vector_type(4))) float f32x4;

#define N_AGENTS 131072
#define HID 128
#define FUT 12
#define OBS 8

constexpr int PAIRS = 4;   // 32-agent pair-tiles per block -> 128 agents/block

__device__ __forceinline__ u16 f2bf(float f) {
    union { float f; unsigned int i; } v; v.f = f;
    unsigned int u = v.i;
    return (u16)((u + 0x7fffu + ((u >> 16) & 1u)) >> 16);
}
__device__ __forceinline__ float vexp2(float x) {
    float r; asm("v_exp_f32 %0, %1" : "=v"(r) : "v"(x)); return r;
}
__device__ __forceinline__ float vrcp(float x) {
    float r; asm("v_rcp_f32 %0, %1" : "=v"(r) : "v"(x)); return r;
}
__device__ __forceinline__ float sigm(float x) {
    return vrcp(1.0f + vexp2(-1.4426950408889634f * x));
}
__device__ __forceinline__ float tanh_(float x) {
    return 2.0f * vrcp(1.0f + vexp2(-2.8853900817779268f * x)) - 1.0f;
}

__launch_bounds__(512, 2)
__global__ void lstm_dec_kernel(const float* __restrict__ obs,
                                const float* __restrict__ h0g,
                                const float* __restrict__ Wih,
                                const float* __restrict__ Whh,
                                const float* __restrict__ bih,
                                const float* __restrict__ bhh,
                                const float* __restrict__ Wout,
                                const float* __restrict__ bout,
                                float* __restrict__ dout)
{
    __shared__ short8 hb[2][32][17];     // h double-buffer, rows padded to 272B
    __shared__ float  xt[32][2];
    __shared__ float  ot[FUT][32][2];

    const int tid  = threadIdx.x;
    const int lane = tid & 63;
    const int wv   = tid >> 6;      // wave 0..7, owns hidden [16*wv, 16*wv+16)
    const int r    = lane & 15;
    const int kb   = lane >> 4;

    const float bout0 = bout[0];
    const float bout1 = bout[1];

    float wih0[4], wih1[4], beff[4];
    int cols[4];
#pragma unroll
    for (int nt = 0; nt < 4; ++nt) {
        int c = nt * HID + wv * 16 + r;
        cols[nt] = c;
        wih0[nt] = Wih[c * 2 + 0];
        wih1[nt] = Wih[c * 2 + 1];
        beff[nt] = bih[c] + bhh[c] + wih0[nt] * bout0 + wih1[nt] * bout1;
    }

    // W_eff = W_hh + W_ih @ W_out fragments (bf16): 64 VGPR; outb: 16
    short8 bfrag[4][4];
    short8 outb[4];
#pragma unroll
    for (int kf = 0; kf < 4; ++kf) {
        const int k0 = kf * 32 + kb * 8;
        float wo0[8], wo1[8];
        short8 ob;
#pragma unroll
        for (int j = 0; j < 8; ++j) {
            wo0[j] = Wout[0 * HID + k0 + j];
            wo1[j] = Wout[1 * HID + k0 + j];
            float sel = (r == 0) ? wo0[j] : ((r == 1) ? wo1[j] : 0.0f);
            ob[j] = (short)f2bf(sel);
        }
        outb[kf] = ob;
#pragma unroll
        for (int nt = 0; nt < 4; ++nt) {
            short8 tt;
#pragma unroll
            for (int j = 0; j < 8; ++j) {
                float f = Whh[(size_t)cols[nt] * HID + k0 + j]
                        + wih0[nt] * wo0[j] + wih1[nt] * wo1[j];
                tt[j] = (short)f2bf(f);
            }
            bfrag[nt][kf] = tt;
        }
    }

#define LOAD_A(rb)                                                   \
    short8 aA[4], aB[4];                                             \
    _Pragma("unroll")                                                \
    for (int kf = 0; kf < 4; ++kf) {                                 \
        aA[kf] = hb[rb][r][kf * 4 + kb];                             \
        aB[kf] = hb[rb][16 + r][kf * 4 + kb];                        \
    }

#define GATES()                                                      \
    f32x4 accA[4], accB[4];                                          \
    _Pragma("unroll")                                                \
    for (int nt = 0; nt < 4; ++nt) {                                 \
        accA[nt] = f32x4{beff[nt], beff[nt], beff[nt], beff[nt]};    \
        accB[nt] = accA[nt];                                         \
    }                                                                \
    _Pragma("unroll")                                                \
    for (int kf = 0; kf < 4; ++kf) {                                 \
        _Pragma("unroll")                                            \
        for (int nt = 0; nt < 4; ++nt) {                             \
            accA[nt] = __builtin_amdgcn_mfma_f32_16x16x32_bf16(      \
                aA[kf], bfrag[nt][kf], accA[nt], 0, 0, 0);           \
            accB[nt] = __builtin_amdgcn_mfma_f32_16x16x32_bf16(      \
                aB[kf], bfrag[nt][kf], accB[nt], 0, 0, 0);           \
        }                                                            \
    }

#define OUT_TILE(dst_expr)                                           \
    if (wv == 0) {                                                   \
        f32x4 oacc = {0.f, 0.f, 0.f, 0.f};                           \
        _Pragma("unroll")                                            \
        for (int kf = 0; kf < 4; ++kf)                               \
            oacc = __builtin_amdgcn_mfma_f32_16x16x32_bf16(          \
                aA[kf], outb[kf], oacc, 0, 0, 0);                    \
        if (r < 2) {                                                 \
            const float bo = (r == 0) ? bout0 : bout1;               \
            _Pragma("unroll")                                        \
            for (int q = 0; q < 4; ++q)                              \
                (dst_expr)[kb * 4 + q][r] = oacc[q] + bo;            \
        }                                                            \
    } else if (wv == 1) {                                            \
        f32x4 oacc = {0.f, 0.f, 0.f, 0.f};                           \
        _Pragma("unroll")                                            \
        for (int kf = 0; kf < 4; ++kf)                               \
            oacc = __builtin_amdgcn_mfma_f32_16x16x32_bf16(          \
                aB[kf], outb[kf], oacc, 0, 0, 0);                    \
        if (r < 2) {                                                 \
            const float bo = (r == 0) ? bout0 : bout1;               \
            _Pragma("unroll")                                        \
            for (int q = 0; q < 4; ++q)                              \
                (dst_expr)[16 + kb * 4 + q][r] = oacc[q] + bo;       \
        }                                                            \
    }

#define ACTIV(wb)                                                    \
    {                                                                \
        u16* hbase = (u16*)&hb[wb][0][0];                            \
        _Pragma("unroll")                                            \
        for (int q = 0; q < 4; ++q) {                                \
            float iv = sigm (accA[0][q]);                            \
            float fv = sigm (accA[1][q]);                            \
            float gv = tanh_(accA[2][q]);                            \
            float ov = sigm (accA[3][q]);                            \
            float cn = fv * cfA[q] + iv * gv;                        \
            cfA[q] = cn;                                             \
            hbase[(kb * 4 + q) * 136 + wv * 16 + r] = f2bf(ov * tanh_(cn)); \
            float iv2 = sigm (accB[0][q]);                           \
            float fv2 = sigm (accB[1][q]);                           \
            float gv2 = tanh_(accB[2][q]);                           \
            float ov2 = sigm (accB[3][q]);                           \
            float cn2 = fv2 * cfB[q] + iv2 * gv2;                    \
            cfB[q] = cn2;                                            \
            hbase[(16 + kb * 4 + q) * 136 + wv * 16 + r] = f2bf(ov2 * tanh_(cn2)); \
        }                                                            \
    }

#pragma unroll 1
    for (int t = 0; t < PAIRS; ++t) {
        const int A0 = (blockIdx.x * PAIRS + t) * 32;

        // cooperative h0 preload -> hb[1] (bf16), 32 rows x 128 cols
        {
            int row = tid >> 4;            // 32 rows, 16 threads/row
            int c8  = (tid & 15) * 8;
            const float* hp = h0g + (size_t)(A0 + row) * HID + c8;
            f32x4 lo = *(const f32x4*)hp;
            f32x4 hi = *(const f32x4*)(hp + 4);
            short8 a;
#pragma unroll
            for (int j = 0; j < 4; ++j) { a[j] = (short)f2bf(lo[j]); a[4 + j] = (short)f2bf(hi[j]); }
            hb[1][row][tid & 15] = a;
        }
        // obs x0 prefetch (8 agents per lane)
        float ox0[8], ox1[8];
#pragma unroll
        for (int hh = 0; hh < 2; ++hh)
#pragma unroll
            for (int q = 0; q < 4; ++q) {
                const float* op = obs + ((size_t)(OBS - 1) * N_AGENTS + A0 + hh * 16 + kb * 4 + q) * 2;
                ox0[hh * 4 + q] = op[0];
                ox1[hh * 4 + q] = op[1];
            }
        f32x4 cfA = {0.f, 0.f, 0.f, 0.f};
        f32x4 cfB = {0.f, 0.f, 0.f, 0.f};
        __syncthreads();

        // ---------------- step 0 ----------------
        {
            LOAD_A(1)
            GATES()
            OUT_TILE(xt)
            __syncthreads();   // x~0 visible
#pragma unroll
            for (int hh = 0; hh < 2; ++hh)
#pragma unroll
                for (int q = 0; q < 4; ++q) {
                    float dx0 = ox0[hh * 4 + q] - xt[hh * 16 + kb * 4 + q][0];
                    float dx1 = ox1[hh * 4 + q] - xt[hh * 16 + kb * 4 + q][1];
#pragma unroll
                    for (int nt = 0; nt < 4; ++nt) {
                        float d = dx0 * wih0[nt] + dx1 * wih1[nt];
                        if (hh == 0) accA[nt][q] += d; else accB[nt][q] += d;
                    }
                }
            ACTIV(0)
            __syncthreads();
        }

        // ---------------- steps 1..11 ----------------
#pragma unroll 1
        for (int s = 1; s < FUT; ++s) {
            const int rb = (s + 1) & 1;
            LOAD_A(rb)
            GATES()
            OUT_TILE(ot[s - 1])
            ACTIV(s & 1)
            __syncthreads();
        }

        // ---------------- step 12: out only ----------------
        {
            LOAD_A(1)
            OUT_TILE(ot[FUT - 1])
            __syncthreads();
        }

        // ---------------- coalesced flush: 768 floats ----------------
        {
            const float* otf = &ot[0][0][0];
            int idx = tid;                      // 0..511
            dout[((size_t)(idx >> 6) * N_AGENTS + A0) * 2 + (idx & 63)] = otf[idx];
            idx = tid + 512;
            if (idx < FUT * 64)
                dout[((size_t)(idx >> 6) * N_AGENTS + A0) * 2 + (idx & 63)] = otf[idx];
        }
        // next ot write is >=2 barriers away (s=1 of next pair) — safe
    }
#undef LOAD_A
#undef GATES
#undef OUT_TILE
#undef ACTIV
}

extern "C" void kernel_launch(void* const* d_in, const int* in_sizes, int n_in,
                              void* d_out, int out_size, void* d_ws, size_t ws_size,
                              hipStream_t stream) {
    const float* obs  = (const float*)d_in[0];
    // d_in[1] (fut_traj_rel) is unused by the reference
    const float* h0   = (const float*)d_in[2];
    const float* Wih  = (const float*)d_in[3];
    const float* Whh  = (const float*)d_in[4];
    const float* bih  = (const float*)d_in[5];
    const float* bhh  = (const float*)d_in[6];
    const float* Wout = (const float*)d_in[7];
    const float* bo   = (const float*)d_in[8];
    float* out = (float*)d_out;

    dim3 grid(N_AGENTS / (PAIRS * 32));   // 1024 blocks of 512 threads
    lstm_dec_kernel<<<grid, 512, 0, stream>>>(obs, h0, Wih, Whh, bih, bhh, Wout, bo, out);
}

// Round 6
// 327.879 us; speedup vs baseline: 1.6652x; 1.1367x over previous
//
#include <hip/hip_runtime.h>

typedef unsigned short u16;
typedef __attribute__((ext_vector_type(8))) short short8;
typedef __attribute__((ext_vector_type(4))) float f32x4;

#define N_AGENTS 131072
#define HID 128
#define FUT 12
#define OBS 8

constexpr int PAIRS = 4;   // 32-agent pair-tiles per block -> 128 agents/block
#define NEG_K  (-1.4426950408889634f)   // -log2(e)
#define NEG_2K (-2.8853900817779268f)   // -2*log2(e)

__device__ __forceinline__ u16 f2bf(float f) {   // round-to-nearest-even (setup only)
    union { float f; unsigned int i; } v; v.f = f;
    unsigned int u = v.i;
    return (u16)((u + 0x7fffu + ((u >> 16) & 1u)) >> 16);
}
__device__ __forceinline__ u16 f2bf_h(float f) { // round-half-up (hot path, 2 ops)
    union { float f; unsigned int i; } v; v.f = f;
    return (u16)((v.i + 0x8000u) >> 16);
}
__device__ __forceinline__ float vexp2(float x) {
    float r; asm("v_exp_f32 %0, %1" : "=v"(r) : "v"(x)); return r;
}
__device__ __forceinline__ float vrcp(float x) {
    float r; asm("v_rcp_f32 %0, %1" : "=v"(r) : "v"(x)); return r;
}

__launch_bounds__(512, 2)
__global__ void lstm_dec_kernel(const float* __restrict__ obs,
                                const float* __restrict__ h0g,
                                const float* __restrict__ Wih,
                                const float* __restrict__ Whh,
                                const float* __restrict__ bih,
                                const float* __restrict__ bhh,
                                const float* __restrict__ Wout,
                                const float* __restrict__ bout,
                                float* __restrict__ dout)
{
    __shared__ short8 hb[2][32][17];     // h double-buffer, rows padded to 272B
    __shared__ float  xt[32][2];
    __shared__ float  ot[FUT][32][2];

    const int tid  = threadIdx.x;
    const int lane = tid & 63;
    const int wv   = tid >> 6;      // wave 0..7, owns hidden [16*wv, 16*wv+16)
    const int r    = lane & 15;
    const int kb   = lane >> 4;

    const float bout0 = bout[0];
    const float bout1 = bout[1];

    // gate scale folded into weights: i,f,o -> -K ; g -> -2K  (nt: 0=i,1=f,2=g,3=o)
    const float gsc[4] = {NEG_K, NEG_K, NEG_2K, NEG_K};

    float wihs0[4], wihs1[4];
    f32x4 accInit[4];                // scaled bias as MFMA C-in
#pragma unroll
    for (int nt = 0; nt < 4; ++nt) {
        int c = nt * HID + wv * 16 + r;
        float w0 = Wih[c * 2 + 0];
        float w1 = Wih[c * 2 + 1];
        float be = (bih[c] + bhh[c] + w0 * bout0 + w1 * bout1) * gsc[nt];
        wihs0[nt] = w0 * gsc[nt];
        wihs1[nt] = w1 * gsc[nt];
        accInit[nt] = f32x4{be, be, be, be};
    }
    const float bo = (r == 0) ? bout0 : ((r == 1) ? bout1 : 0.0f);
    const f32x4 oInit = {bo, bo, bo, bo};

    // W_eff = (W_hh + W_ih @ W_out) * gsc  fragments (bf16): 64 VGPR; outb: 16
    short8 bfrag[4][4];
    short8 outb[4];
#pragma unroll
    for (int kf = 0; kf < 4; ++kf) {
        const int k0 = kf * 32 + kb * 8;
        float wo0[8], wo1[8];
        short8 ob;
#pragma unroll
        for (int j = 0; j < 8; ++j) {
            wo0[j] = Wout[0 * HID + k0 + j];
            wo1[j] = Wout[1 * HID + k0 + j];
            float sel = (r == 0) ? wo0[j] : ((r == 1) ? wo1[j] : 0.0f);
            ob[j] = (short)f2bf(sel);
        }
        outb[kf] = ob;
#pragma unroll
        for (int nt = 0; nt < 4; ++nt) {
            int c = nt * HID + wv * 16 + r;
            float s0 = wihs0[nt], s1 = wihs1[nt];   // already scaled
            short8 tt;
#pragma unroll
            for (int j = 0; j < 8; ++j) {
                float f = Whh[(size_t)c * HID + k0 + j] * gsc[nt]
                        + s0 * wo0[j] + s1 * wo1[j];
                tt[j] = (short)f2bf(f);
            }
            bfrag[nt][kf] = tt;
        }
    }

#define LOAD_A(rb)                                                   \
    short8 aA[4], aB[4];                                             \
    _Pragma("unroll")                                                \
    for (int kf = 0; kf < 4; ++kf) {                                 \
        aA[kf] = hb[rb][r][kf * 4 + kb];                             \
        aB[kf] = hb[rb][16 + r][kf * 4 + kb];                        \
    }

#define GATES()                                                      \
    f32x4 accA[4], accB[4];                                          \
    _Pragma("unroll")                                                \
    for (int nt = 0; nt < 4; ++nt) {                                 \
        accA[nt] = __builtin_amdgcn_mfma_f32_16x16x32_bf16(          \
            aA[0], bfrag[nt][0], accInit[nt], 0, 0, 0);              \
        accB[nt] = __builtin_amdgcn_mfma_f32_16x16x32_bf16(          \
            aB[0], bfrag[nt][0], accInit[nt], 0, 0, 0);              \
    }                                                                \
    _Pragma("unroll")                                                \
    for (int kf = 1; kf < 4; ++kf) {                                 \
        _Pragma("unroll")                                            \
        for (int nt = 0; nt < 4; ++nt) {                             \
            accA[nt] = __builtin_amdgcn_mfma_f32_16x16x32_bf16(      \
                aA[kf], bfrag[nt][kf], accA[nt], 0, 0, 0);           \
            accB[nt] = __builtin_amdgcn_mfma_f32_16x16x32_bf16(      \
                aB[kf], bfrag[nt][kf], accB[nt], 0, 0, 0);           \
        }                                                            \
    }

#define OUT_TILE(dst_expr)                                           \
    if (wv == 0) {                                                   \
        f32x4 oacc = __builtin_amdgcn_mfma_f32_16x16x32_bf16(        \
            aA[0], outb[0], oInit, 0, 0, 0);                         \
        _Pragma("unroll")                                            \
        for (int kf = 1; kf < 4; ++kf)                               \
            oacc = __builtin_amdgcn_mfma_f32_16x16x32_bf16(          \
                aA[kf], outb[kf], oacc, 0, 0, 0);                    \
        if (r < 2) {                                                 \
            _Pragma("unroll")                                        \
            for (int q = 0; q < 4; ++q)                              \
                (dst_expr)[kb * 4 + q][r] = oacc[q];                 \
        }                                                            \
    } else if (wv == 1) {                                            \
        f32x4 oacc = __builtin_amdgcn_mfma_f32_16x16x32_bf16(        \
            aB[0], outb[0], oInit, 0, 0, 0);                         \
        _Pragma("unroll")                                            \
        for (int kf = 1; kf < 4; ++kf)                               \
            oacc = __builtin_amdgcn_mfma_f32_16x16x32_bf16(          \
                aB[kf], outb[kf], oacc, 0, 0, 0);                    \
        if (r < 2) {                                                 \
            _Pragma("unroll")                                        \
            for (int q = 0; q < 4; ++q)                              \
                (dst_expr)[16 + kb * 4 + q][r] = oacc[q];            \
        }                                                            \
    }

// merged-rcp LSTM cell: 5 exp + 2 rcp (scaled gates arrive as exp2 args)
#define CELL(sI, sF, sG, sO, cref, dst_u16)                          \
    {                                                                \
        float Ei = vexp2(sI);                                        \
        float Ef = vexp2(sF);                                        \
        float Gg = vexp2(sG);                                        \
        float Eo = vexp2(sO);                                        \
        float t1 = 1.0f + Ei, t2 = 1.0f + Gg, t3 = 1.0f + Ef;        \
        float t12 = t1 * t2;                                         \
        float num = t12 * (cref) + t3 * (1.0f - Gg);                 \
        float R1  = vrcp(t12 * t3);                                  \
        float cn  = num * R1;                                        \
        (cref) = cn;                                                 \
        float Gc = vexp2(NEG_2K * cn);                               \
        float R2 = vrcp((1.0f + Eo) * (1.0f + Gc));                  \
        (dst_u16) = f2bf_h((1.0f - Gc) * R2);                        \
    }

#define ACTIV(wb)                                                    \
    {                                                                \
        u16* hbase = (u16*)&hb[wb][0][0];                            \
        _Pragma("unroll")                                            \
        for (int q = 0; q < 4; ++q) {                                \
            CELL(accA[0][q], accA[1][q], accA[2][q], accA[3][q],     \
                 cfA[q], hbase[(kb * 4 + q) * 136 + wv * 16 + r])    \
            CELL(accB[0][q], accB[1][q], accB[2][q], accB[3][q],     \
                 cfB[q], hbase[(16 + kb * 4 + q) * 136 + wv * 16 + r]) \
        }                                                            \
    }

#pragma unroll 1
    for (int t = 0; t < PAIRS; ++t) {
        const int A0 = (blockIdx.x * PAIRS + t) * 32;

        // cooperative h0 preload -> hb[1] (bf16), 32 rows x 128 cols
        {
            int row = tid >> 4;            // 32 rows, 16 threads/row
            int c8  = (tid & 15) * 8;
            const float* hp = h0g + (size_t)(A0 + row) * HID + c8;
            f32x4 lo = *(const f32x4*)hp;
            f32x4 hi = *(const f32x4*)(hp + 4);
            short8 a;
#pragma unroll
            for (int j = 0; j < 4; ++j) { a[j] = (short)f2bf(lo[j]); a[4 + j] = (short)f2bf(hi[j]); }
            hb[1][row][tid & 15] = a;
        }
        // obs x0 prefetch (8 agents per lane)
        float ox0[8], ox1[8];
#pragma unroll
        for (int hh = 0; hh < 2; ++hh)
#pragma unroll
            for (int q = 0; q < 4; ++q) {
                const float* op = obs + ((size_t)(OBS - 1) * N_AGENTS + A0 + hh * 16 + kb * 4 + q) * 2;
                ox0[hh * 4 + q] = op[0];
                ox1[hh * 4 + q] = op[1];
            }
        f32x4 cfA = {0.f, 0.f, 0.f, 0.f};
        f32x4 cfB = {0.f, 0.f, 0.f, 0.f};
        __syncthreads();

        // ---------------- step 0 ----------------
        {
            LOAD_A(1)
            GATES()
            OUT_TILE(xt)
            __syncthreads();   // x~0 visible
#pragma unroll
            for (int hh = 0; hh < 2; ++hh)
#pragma unroll
                for (int q = 0; q < 4; ++q) {
                    float dx0 = ox0[hh * 4 + q] - xt[hh * 16 + kb * 4 + q][0];
                    float dx1 = ox1[hh * 4 + q] - xt[hh * 16 + kb * 4 + q][1];
#pragma unroll
                    for (int nt = 0; nt < 4; ++nt) {
                        float d = dx0 * wihs0[nt] + dx1 * wihs1[nt];
                        if (hh == 0) accA[nt][q] += d; else accB[nt][q] += d;
                    }
                }
            ACTIV(0)
            __syncthreads();
        }

        // ---------------- steps 1..11 ----------------
#pragma unroll 1
        for (int s = 1; s < FUT; ++s) {
            const int rb = (s + 1) & 1;
            LOAD_A(rb)
            GATES()
            OUT_TILE(ot[s - 1])
            ACTIV(s & 1)
            __syncthreads();
        }

        // ---------------- step 12: out only ----------------
        {
            LOAD_A(1)
            OUT_TILE(ot[FUT - 1])
            __syncthreads();
        }

        // ---------------- coalesced flush: 768 floats ----------------
        {
            const float* otf = &ot[0][0][0];
            int idx = tid;                      // 0..511
            dout[((size_t)(idx >> 6) * N_AGENTS + A0) * 2 + (idx & 63)] = otf[idx];
            idx = tid + 512;
            if (idx < FUT * 64)
                dout[((size_t)(idx >> 6) * N_AGENTS + A0) * 2 + (idx & 63)] = otf[idx];
        }
        // next ot write is >=2 barriers away (s=1 of next pair) — safe
    }
#undef LOAD_A
#undef GATES
#undef OUT_TILE
#undef ACTIV
#undef CELL
}

extern "C" void kernel_launch(void* const* d_in, const int* in_sizes, int n_in,
                              void* d_out, int out_size, void* d_ws, size_t ws_size,
                              hipStream_t stream) {
    const float* obs  = (const float*)d_in[0];
    // d_in[1] (fut_traj_rel) is unused by the reference
    const float* h0   = (const float*)d_in[2];
    const float* Wih  = (const float*)d_in[3];
    const float* Whh  = (const float*)d_in[4];
    const float* bih  = (const float*)d_in[5];
    const float* bhh  = (const float*)d_in[6];
    const float* Wout = (const float*)d_in[7];
    const float* bo   = (const float*)d_in[8];
    float* out = (float*)d_out;

    dim3 grid(N_AGENTS / (PAIRS * 32));   // 1024 blocks of 512 threads
    lstm_dec_kernel<<<grid, 512, 0, stream>>>(obs, h0, Wih, Whh, bih, bhh, Wout, bo, out);
}

// Round 7
// 295.309 us; speedup vs baseline: 1.8489x; 1.1103x over previous
//
#include <hip/hip_runtime.h>

typedef unsigned short u16;
typedef __attribute__((ext_vector_type(8))) short short8;
typedef __attribute__((ext_vector_type(4))) float f32x4;
typedef __attribute__((ext_vector_type(2))) float f32x2;

#define N_AGENTS 131072
#define HID 128
#define FUT 12
#define OBS 8

constexpr int PAIRS = 4;   // 32-agent pair-tiles per block -> 128 agents/block
#define NEG_K  (-1.4426950408889634f)   // -log2(e)
#define NEG_2K (-2.8853900817779268f)   // -2*log2(e)

__device__ __forceinline__ u16 f2bf(float f) {   // RNE (setup only)
    union { float f; unsigned int i; } v; v.f = f;
    unsigned int u = v.i;
    return (u16)((u + 0x7fffu + ((u >> 16) & 1u)) >> 16);
}
__device__ __forceinline__ float bexp2(float x) {
#if __has_builtin(__builtin_amdgcn_exp2f)
    return __builtin_amdgcn_exp2f(x);
#else
    float r; asm("v_exp_f32 %0, %1" : "=v"(r) : "v"(x)); return r;
#endif
}
__device__ __forceinline__ float brcp(float x) {
#if __has_builtin(__builtin_amdgcn_rcpf)
    return __builtin_amdgcn_rcpf(x);
#else
    float r; asm("v_rcp_f32 %0, %1" : "=v"(r) : "v"(x)); return r;
#endif
}
__device__ __forceinline__ unsigned cvtpk(float lo, float hi) {  // 2x f32 -> packed bf16 (RNE)
    unsigned r; asm("v_cvt_pk_bf16_f32 %0, %1, %2" : "=v"(r) : "v"(lo), "v"(hi)); return r;
}

__launch_bounds__(512, 2)
__global__ void lstm_dec_kernel(const float* __restrict__ obs,
                                const float* __restrict__ h0g,
                                const float* __restrict__ Wih,
                                const float* __restrict__ Whh,
                                const float* __restrict__ bih,
                                const float* __restrict__ bhh,
                                const float* __restrict__ Wout,
                                const float* __restrict__ bout,
                                float* __restrict__ dout)
{
    __shared__ short8 hb[2][32][17];     // h double-buffer, rows padded to 272B
    __shared__ float  xt[32][2];
    __shared__ float  ot[FUT][32][2];

    const int tid  = threadIdx.x;
    const int lane = tid & 63;
    const int wv   = tid >> 6;      // wave 0..7, owns hidden [16*wv, 16*wv+16)
    const int r    = lane & 15;
    const int kb   = lane >> 4;

    const float bout0 = bout[0];
    const float bout1 = bout[1];

    // gate scale folded into weights: i,f,o -> -K ; g -> -2K  (nt: 0=i,1=f,2=g,3=o)
    const float gsc[4] = {NEG_K, NEG_K, NEG_2K, NEG_K};

    float wihs0[4], wihs1[4];
    f32x4 accInit[4];                // scaled bias as MFMA C-in
#pragma unroll
    for (int nt = 0; nt < 4; ++nt) {
        int c = nt * HID + wv * 16 + r;
        float w0 = Wih[c * 2 + 0];
        float w1 = Wih[c * 2 + 1];
        float be = (bih[c] + bhh[c] + w0 * bout0 + w1 * bout1) * gsc[nt];
        wihs0[nt] = w0 * gsc[nt];
        wihs1[nt] = w1 * gsc[nt];
        accInit[nt] = f32x4{be, be, be, be};
    }
    const float bo = (r == 0) ? bout0 : ((r == 1) ? bout1 : 0.0f);
    const f32x4 oInit = {bo, bo, bo, bo};

    // W_eff = (W_hh + W_ih @ W_out) * gsc  fragments (bf16): 64 VGPR; outb: 16
    short8 bfrag[4][4];
    short8 outb[4];
#pragma unroll
    for (int kf = 0; kf < 4; ++kf) {
        const int k0 = kf * 32 + kb * 8;
        float wo0[8], wo1[8];
        short8 ob;
#pragma unroll
        for (int j = 0; j < 8; ++j) {
            wo0[j] = Wout[0 * HID + k0 + j];
            wo1[j] = Wout[1 * HID + k0 + j];
            float sel = (r == 0) ? wo0[j] : ((r == 1) ? wo1[j] : 0.0f);
            ob[j] = (short)f2bf(sel);
        }
        outb[kf] = ob;
#pragma unroll
        for (int nt = 0; nt < 4; ++nt) {
            int c = nt * HID + wv * 16 + r;
            float s0 = wihs0[nt], s1 = wihs1[nt];   // already scaled
            short8 tt;
#pragma unroll
            for (int j = 0; j < 8; ++j) {
                float f = Whh[(size_t)c * HID + k0 + j] * gsc[nt]
                        + s0 * wo0[j] + s1 * wo1[j];
                tt[j] = (short)f2bf(f);
            }
            bfrag[nt][kf] = tt;
        }
    }

#define LOAD_A(rb)                                                   \
    short8 aA[4], aB[4];                                             \
    _Pragma("unroll")                                                \
    for (int kf = 0; kf < 4; ++kf) {                                 \
        aA[kf] = hb[rb][r][kf * 4 + kb];                             \
        aB[kf] = hb[rb][16 + r][kf * 4 + kb];                        \
    }

#define GATES()                                                      \
    f32x4 accA[4], accB[4];                                          \
    _Pragma("unroll")                                                \
    for (int nt = 0; nt < 4; ++nt) {                                 \
        accA[nt] = __builtin_amdgcn_mfma_f32_16x16x32_bf16(          \
            aA[0], bfrag[nt][0], accInit[nt], 0, 0, 0);              \
        accB[nt] = __builtin_amdgcn_mfma_f32_16x16x32_bf16(          \
            aB[0], bfrag[nt][0], accInit[nt], 0, 0, 0);              \
    }                                                                \
    _Pragma("unroll")                                                \
    for (int kf = 1; kf < 4; ++kf) {                                 \
        _Pragma("unroll")                                            \
        for (int nt = 0; nt < 4; ++nt) {                             \
            accA[nt] = __builtin_amdgcn_mfma_f32_16x16x32_bf16(      \
                aA[kf], bfrag[nt][kf], accA[nt], 0, 0, 0);           \
            accB[nt] = __builtin_amdgcn_mfma_f32_16x16x32_bf16(      \
                aB[kf], bfrag[nt][kf], accB[nt], 0, 0, 0);           \
        }                                                            \
    }

#define OUT_TILE(dst_expr)                                           \
    if (wv == 0) {                                                   \
        f32x4 oacc = __builtin_amdgcn_mfma_f32_16x16x32_bf16(        \
            aA[0], outb[0], oInit, 0, 0, 0);                         \
        _Pragma("unroll")                                            \
        for (int kf = 1; kf < 4; ++kf)                               \
            oacc = __builtin_amdgcn_mfma_f32_16x16x32_bf16(          \
                aA[kf], outb[kf], oacc, 0, 0, 0);                    \
        if (r < 2) {                                                 \
            _Pragma("unroll")                                        \
            for (int q = 0; q < 4; ++q)                              \
                (dst_expr)[kb * 4 + q][r] = oacc[q];                 \
        }                                                            \
    } else if (wv == 1) {                                            \
        f32x4 oacc = __builtin_amdgcn_mfma_f32_16x16x32_bf16(        \
            aB[0], outb[0], oInit, 0, 0, 0);                         \
        _Pragma("unroll")                                            \
        for (int kf = 1; kf < 4; ++kf)                               \
            oacc = __builtin_amdgcn_mfma_f32_16x16x32_bf16(          \
                aB[kf], outb[kf], oacc, 0, 0, 0);                    \
        if (r < 2) {                                                 \
            _Pragma("unroll")                                        \
            for (int q = 0; q < 4; ++q)                              \
                (dst_expr)[16 + kb * 4 + q][r] = oacc[q];            \
        }                                                            \
    }

// packed pair-cell: A,B cells at same q on f32x2 (v_pk_*), 14 scalar trans
#define CELL2(q)                                                     \
    {                                                                \
        f32x2 Ei = {bexp2(accA[0][q]), bexp2(accB[0][q])};           \
        f32x2 Ef = {bexp2(accA[1][q]), bexp2(accB[1][q])};           \
        f32x2 Gg = {bexp2(accA[2][q]), bexp2(accB[2][q])};           \
        f32x2 Eo = {bexp2(accA[3][q]), bexp2(accB[3][q])};           \
        f32x2 c2 = {cfA[q], cfB[q]};                                 \
        f32x2 t1 = 1.0f + Ei;                                        \
        f32x2 t2 = 1.0f + Gg;                                        \
        f32x2 t3 = 1.0f + Ef;                                        \
        f32x2 t12 = t1 * t2;                                         \
        f32x2 num = t12 * c2 + t3 * (1.0f - Gg);                     \
        f32x2 den = t12 * t3;                                        \
        f32x2 R1 = {brcp(den.x), brcp(den.y)};                       \
        f32x2 cn = num * R1;                                         \
        cfA[q] = cn.x; cfB[q] = cn.y;                                \
        f32x2 ga = NEG_2K * cn;                                      \
        f32x2 Gc = {bexp2(ga.x), bexp2(ga.y)};                       \
        f32x2 u1 = (1.0f + Eo) * (1.0f + Gc);                        \
        f32x2 R2 = {brcp(u1.x), brcp(u1.y)};                         \
        f32x2 hv = (1.0f - Gc) * R2;                                 \
        unsigned pk = cvtpk(hv.x, hv.y);                             \
        hbase[(kb * 4 + q) * 136 + hcol] = (u16)pk;                  \
        hbase[(16 + kb * 4 + q) * 136 + hcol] = (u16)(pk >> 16);     \
    }

#define ACTIV(wb)                                                    \
    {                                                                \
        u16* hbase = (u16*)&hb[wb][0][0];                            \
        const int hcol = wv * 16 + r;                                \
        CELL2(0) CELL2(1) CELL2(2) CELL2(3)                          \
    }

#pragma unroll 1
    for (int t = 0; t < PAIRS; ++t) {
        const int A0 = (blockIdx.x * PAIRS + t) * 32;

        // cooperative h0 preload -> hb[1] (bf16), 32 rows x 128 cols
        {
            int row = tid >> 4;            // 32 rows, 16 threads/row
            int c8  = (tid & 15) * 8;
            const float* hp = h0g + (size_t)(A0 + row) * HID + c8;
            f32x4 lo = *(const f32x4*)hp;
            f32x4 hi = *(const f32x4*)(hp + 4);
            short8 a;
            unsigned* ap = (unsigned*)&a;
            ap[0] = cvtpk(lo[0], lo[1]);
            ap[1] = cvtpk(lo[2], lo[3]);
            ap[2] = cvtpk(hi[0], hi[1]);
            ap[3] = cvtpk(hi[2], hi[3]);
            hb[1][row][tid & 15] = a;
        }
        // obs x0 prefetch (8 agents per lane)
        float ox0[8], ox1[8];
#pragma unroll
        for (int hh = 0; hh < 2; ++hh)
#pragma unroll
            for (int q = 0; q < 4; ++q) {
                const float* op = obs + ((size_t)(OBS - 1) * N_AGENTS + A0 + hh * 16 + kb * 4 + q) * 2;
                ox0[hh * 4 + q] = op[0];
                ox1[hh * 4 + q] = op[1];
            }
        f32x4 cfA = {0.f, 0.f, 0.f, 0.f};
        f32x4 cfB = {0.f, 0.f, 0.f, 0.f};
        __syncthreads();

        // ---------------- step 0 ----------------
        {
            LOAD_A(1)
            GATES()
            OUT_TILE(xt)
            __syncthreads();   // x~0 visible
#pragma unroll
            for (int hh = 0; hh < 2; ++hh)
#pragma unroll
                for (int q = 0; q < 4; ++q) {
                    float dx0 = ox0[hh * 4 + q] - xt[hh * 16 + kb * 4 + q][0];
                    float dx1 = ox1[hh * 4 + q] - xt[hh * 16 + kb * 4 + q][1];
#pragma unroll
                    for (int nt = 0; nt < 4; ++nt) {
                        float d = dx0 * wihs0[nt] + dx1 * wihs1[nt];
                        if (hh == 0) accA[nt][q] += d; else accB[nt][q] += d;
                    }
                }
            ACTIV(0)
            __syncthreads();
        }

        // ---------------- steps 1..11 ----------------
#pragma unroll 1
        for (int s = 1; s < FUT; ++s) {
            const int rb = (s + 1) & 1;
            LOAD_A(rb)
            GATES()
            OUT_TILE(ot[s - 1])
            ACTIV(s & 1)
            __syncthreads();
        }

        // ---------------- step 12: out only ----------------
        {
            LOAD_A(1)
            OUT_TILE(ot[FUT - 1])
            __syncthreads();
        }

        // ---------------- coalesced flush: 768 floats ----------------
        {
            const float* otf = &ot[0][0][0];
            int idx = tid;                      // 0..511
            dout[((size_t)(idx >> 6) * N_AGENTS + A0) * 2 + (idx & 63)] = otf[idx];
            idx = tid + 512;
            if (idx < FUT * 64)
                dout[((size_t)(idx >> 6) * N_AGENTS + A0) * 2 + (idx & 63)] = otf[idx];
        }
        // next ot write is >=2 barriers away (s=1 of next pair) — safe
    }
#undef LOAD_A
#undef GATES
#undef OUT_TILE
#undef ACTIV
#undef CELL2
}

extern "C" void kernel_launch(void* const* d_in, const int* in_sizes, int n_in,
                              void* d_out, int out_size, void* d_ws, size_t ws_size,
                              hipStream_t stream) {
    const float* obs  = (const float*)d_in[0];
    // d_in[1] (fut_traj_rel) is unused by the reference
    const float* h0   = (const float*)d_in[2];
    const float* Wih  = (const float*)d_in[3];
    const float* Whh  = (const float*)d_in[4];
    const float* bih  = (const float*)d_in[5];
    const float* bhh  = (const float*)d_in[6];
    const float* Wout = (const float*)d_in[7];
    const float* bo   = (const float*)d_in[8];
    float* out = (float*)d_out;

    dim3 grid(N_AGENTS / (PAIRS * 32));   // 1024 blocks of 512 threads
    lstm_dec_kernel<<<grid, 512, 0, stream>>>(obs, h0, Wih, Whh, bih, bhh, Wout, bo, out);
}